// Round 6
// baseline (253.731 us; speedup 1.0000x reference)
//
#include <hip/hip_runtime.h>

// BilinearSamplerLayer: image [16,256,256,32] f32, flow [16,256,256,2] f32
// -> out [16,256,256,32] f32.
// PPT=1 (R2 baseline structure: 83.6us, 16 VGPR — PPT=4 regressed to 91us)
// + XCD-aware block swizzle: blockIdx round-robins the 8 XCDs, so remap
//   bid = (orig%8)*4096 + orig/8  => XCD k owns a contiguous 512-row band
//   (2 batch images) processed top-to-bottom. Flow displacement is
//   0.3*N(0,1) in [-1,1] coords ~= +-38 px, so the live source window is
//   ~110 rows * 32KB = ~3.5MB — fits the 4MB per-XCD L2. The ~4x per-row
//   reuse becomes L2 hits instead of L3/fabric traffic.
// + non-temporal stores keep the 128MB write stream from evicting that
//   L2-resident sliding window.

using f32x4 = __attribute__((ext_vector_type(4))) float;

__global__ __launch_bounds__(256) void bilinear_sampler_kernel(
    const float* __restrict__ image,
    const float* __restrict__ flow,
    float* __restrict__ out)
{
    constexpr int H = 256, W = 256, C = 32;
    constexpr int NXCD = 8;
    constexpr int NWG  = 32768;          // 8,388,608 threads / 256
    constexpr int WPX  = NWG / NXCD;     // 4096 blocks per XCD

    // XCD swizzle (bijective: NWG % 8 == 0)
    const int orig = blockIdx.x;
    const int bid  = (orig & (NXCD - 1)) * WPX + (orig >> 3);

    const int gid = bid * 256 + threadIdx.x;
    const int pid = gid >> 3;                         // pixel id [0, 1M)
    const int cq  = (gid & 7) << 2;                   // channel offset 0..28

    const int b   = pid >> 16;
    const int rem = pid & 65535;
    const int yi  = rem >> 8;
    const int xi  = rem & 255;

    const float2 f = *reinterpret_cast<const float2*>(flow + (size_t)pid * 2);

    // base grid: linspace(-1,1,N) -> -1 + 2*i/(N-1)
    const float x_base = fmaf((float)xi, 2.0f / 255.0f, -1.0f);
    const float y_base = fmaf((float)yi, 2.0f / 255.0f, -1.0f);

    float x = fmaf(0.3f, f.x, x_base);
    float y = fmaf(0.3f, f.y, y_base);
    x = (x + 1.0f) * (0.5f * (float)W);   // reference uses W/2, not (W-1)/2
    y = (y + 1.0f) * (0.5f * (float)H);

    int x0 = (int)floorf(x);
    int y0 = (int)floorf(y);
    int x1 = x0 + 1;
    int y1 = y0 + 1;
    x0 = min(max(x0, 0), W - 1);
    x1 = min(max(x1, 0), W - 1);
    y0 = min(max(y0, 0), H - 1);
    y1 = min(max(y1, 0), H - 1);

    const float x0f = (float)x0, x1f = (float)x1;
    const float y0f = (float)y0, y1f = (float)y1;
    const float wa = (x1f - x) * (y1f - y);
    const float wb = (x1f - x) * (y - y0f);
    const float wc = (x - x0f) * (y1f - y);
    const float wd = (x - x0f) * (y - y0f);

    const int base = b << 16;
    const size_t row0 = (size_t)(base + y0 * W) * C;
    const size_t row1 = (size_t)(base + y1 * W) * C;

    const f32x4 Ia = *reinterpret_cast<const f32x4*>(image + row0 + (size_t)x0 * C + cq);
    const f32x4 Ib = *reinterpret_cast<const f32x4*>(image + row1 + (size_t)x0 * C + cq);
    const f32x4 Ic = *reinterpret_cast<const f32x4*>(image + row0 + (size_t)x1 * C + cq);
    const f32x4 Id = *reinterpret_cast<const f32x4*>(image + row1 + (size_t)x1 * C + cq);

    const f32x4 o = wa * Ia + wb * Ib + wc * Ic + wd * Id;
    __builtin_nontemporal_store(o, reinterpret_cast<f32x4*>(out + (size_t)pid * C + cq));
}

extern "C" void kernel_launch(void* const* d_in, const int* in_sizes, int n_in,
                              void* d_out, int out_size, void* d_ws, size_t ws_size,
                              hipStream_t stream) {
    const float* image = (const float*)d_in[0];
    const float* flow  = (const float*)d_in[1];
    float* out = (float*)d_out;

    const int blocks = 32768; // 8,388,608 threads / 256
    bilinear_sampler_kernel<<<blocks, 256, 0, stream>>>(image, flow, out);
}